// Round 1
// baseline (54.054 us; speedup 1.0000x reference)
//
#include <hip/hip_runtime.h>
#include <math.h>

#define BB 32
#define LL 512
#define HH 352
#define WW 1216
#define NLINES (BB * LL)          // 16384
#define WAVES_PER_BLOCK 4
#define NBLOCKS (NLINES / WAVES_PER_BLOCK)  // 4096

__device__ __forceinline__ float line_degree(int x0, int y0, int x1, int y1) {
    // Replicates: slopes = |(y1f - y0f) / (x1f - x0f + 1e-6)|
    //             degrees = (arctan(slopes) * 180.0 / pi) % 90.0
    float slope = fabsf(((float)y1 - (float)y0) / ((float)x1 - (float)x0 + 1e-6f));
    float deg = (atanf(slope) * 180.0f) / 3.14159274101257324f;  // f32(pi)
    return fmodf(deg, 90.0f);
}

__global__ void deg_max_kernel(const int* __restrict__ lines, float* __restrict__ mx) {
    __shared__ float red[LL];
    int b = blockIdx.x;
    int t = threadIdx.x;
    int4 ln = ((const int4*)lines)[b * LL + t];
    int x0 = min(max(ln.x, 0), WW - 1);
    int y0 = min(max(ln.y, 0), HH - 1);
    int x1 = min(max(ln.z, 0), WW - 1);
    int y1 = min(max(ln.w, 0), HH - 1);
    red[t] = line_degree(x0, y0, x1, y1);
    __syncthreads();
    for (int s = LL / 2; s > 0; s >>= 1) {
        if (t < s) red[t] = fmaxf(red[t], red[t + s]);
        __syncthreads();
    }
    if (t == 0) mx[b] = red[0];
}

__global__ void __launch_bounds__(256) line_walk_kernel(
        const float* __restrict__ pred, const int* __restrict__ lines,
        const float* __restrict__ mx, float* __restrict__ partials) {
    __shared__ float wsum[WAVES_PER_BLOCK];
    int lane = threadIdx.x & 63;
    int w = threadIdx.x >> 6;
    int g = blockIdx.x * WAVES_PER_BLOCK + w;   // global line id
    int b = g >> 9;                              // / LL

    int4 ln = ((const int4*)lines)[g];
    int x0 = min(max(ln.x, 0), WW - 1);
    int y0 = min(max(ln.y, 0), HH - 1);
    int x1 = min(max(ln.z, 0), WW - 1);
    int y1 = min(max(ln.w, 0), HH - 1);

    int dx = abs(x1 - x0), dy = abs(y1 - y0);
    bool xm = dx > dy;
    int dmaj = xm ? dx : dy;
    int dmin = xm ? dy : dx;
    int sx = (x1 > x0) - (x1 < x0);
    int sy = (y1 > y0) - (y1 < y0);
    int smaj = xm ? sx : sy;
    int smin = xm ? sy : sx;
    int maj0 = xm ? x0 : y0;
    int min0 = xm ? y0 : x0;

    const float* __restrict__ p = pred + (size_t)b * (HH * WW);

    float s = 0.0f;
    if (dmaj > 0) {
        int den = 2 * dmaj;
        int tdm = 2 * dmin;
        for (int i = lane; i < dmaj; i += 64) {
            int num0 = tdm * i + dmaj;
            int q0 = (int)((unsigned)num0 / (unsigned)den);
            // q increments by at most 1 per step (dmin <= dmaj)
            int q1 = q0 + ((num0 + tdm >= den * (q0 + 1)) ? 1 : 0);
            int mjA = maj0 + smaj * i;
            int mnA = min0 + smin * q0;
            int mjB = mjA + smaj;
            int mnB = min0 + smin * q1;
            int xA = xm ? mjA : mnA, yA = xm ? mnA : mjA;
            int xB = xm ? mjB : mnB, yB = xm ? mnB : mjB;
            float vA = p[yA * WW + xA];
            float vB = p[yB * WW + xB];
            s += fabsf(vB - vA);
        }
    }
    // wave-level sum reduction (64 lanes)
    #pragma unroll
    for (int off = 32; off > 0; off >>= 1) s += __shfl_down(s, off);

    if (lane == 0) {
        // end_diff mask: vals[0] = pred[y0,x0], vals[-1] = pred[y1,x1]
        float vf = p[y0 * WW + x0];
        float vl = p[y1 * WW + x1];
        if (fabsf(vf - vl) < 0.5f) s = 0.0f;

        float deg = line_degree(x0, y0, x1, y1);
        float mxv = mx[b];
        float skewed = powf(deg, 1.5f) / powf(mxv + 1.0f, 0.5f);
        float t = fabsf(skewed - 45.0f);
        float h = 90.0f - powf(powf(t, 2.5f), 0.4f);
        float wgt = powf(h * (1.0f / 300.0f), 4.0f);
        wsum[w] = wgt * s;
    }
    __syncthreads();
    if (threadIdx.x == 0) {
        float acc = 0.0f;
        #pragma unroll
        for (int i = 0; i < WAVES_PER_BLOCK; ++i) acc += wsum[i];
        partials[blockIdx.x] = acc;
    }
}

__global__ void final_reduce_kernel(const float* __restrict__ partials,
                                    float* __restrict__ out) {
    __shared__ float red[256];
    int t = threadIdx.x;
    float s = 0.0f;
    for (int i = t; i < NBLOCKS; i += 256) s += partials[i];
    red[t] = s;
    __syncthreads();
    for (int k = 128; k > 0; k >>= 1) {
        if (t < k) red[t] += red[t + k];
        __syncthreads();
    }
    if (t == 0) out[0] = red[0];
}

extern "C" void kernel_launch(void* const* d_in, const int* in_sizes, int n_in,
                              void* d_out, int out_size, void* d_ws, size_t ws_size,
                              hipStream_t stream) {
    const float* pred = (const float*)d_in[0];
    const int* lines = (const int*)d_in[1];
    float* out = (float*)d_out;
    float* ws = (float*)d_ws;
    float* mx = ws;                 // 32 floats
    float* partials = ws + 32;      // 4096 floats

    deg_max_kernel<<<BB, LL, 0, stream>>>(lines, mx);
    line_walk_kernel<<<NBLOCKS, 256, 0, stream>>>(pred, lines, mx, partials);
    final_reduce_kernel<<<1, 256, 0, stream>>>(partials, out);
}

// Round 4
// 52.489 us; speedup vs baseline: 1.0298x; 1.0298x over previous
//
#include <hip/hip_runtime.h>
#include <math.h>

#define BB 32
#define LL 512
#define HH 352
#define WW 1216
#define NLINES (BB * LL)          // 16384
#define WAVES_PER_BLOCK 4
#define NBLOCKS (NLINES / WAVES_PER_BLOCK)  // 4096

__device__ __forceinline__ float line_degree(int x0, int y0, int x1, int y1) {
    // Replicates: slopes = |(y1f - y0f) / (x1f - x0f + 1e-6)|
    //             degrees = (arctan(slopes) * 180.0 / pi) % 90.0
    float slope = fabsf(((float)y1 - (float)y0) / ((float)x1 - (float)x0 + 1e-6f));
    float deg = (atanf(slope) * 180.0f) / 3.14159274101257324f;  // f32(pi)
    return fmodf(deg, 90.0f);
}

__global__ void deg_max_kernel(const int* __restrict__ lines, float* __restrict__ mx) {
    __shared__ float red[LL];
    int b = blockIdx.x;
    int t = threadIdx.x;
    int4 ln = ((const int4*)lines)[b * LL + t];
    int x0 = min(max(ln.x, 0), WW - 1);
    int y0 = min(max(ln.y, 0), HH - 1);
    int x1 = min(max(ln.z, 0), WW - 1);
    int y1 = min(max(ln.w, 0), HH - 1);
    red[t] = line_degree(x0, y0, x1, y1);
    __syncthreads();
    for (int s = LL / 2; s > 0; s >>= 1) {
        if (t < s) red[t] = fmaxf(red[t], red[t + s]);
        __syncthreads();
    }
    if (t == 0) mx[b] = red[0];
}

__global__ void __launch_bounds__(256) line_walk_kernel(
        const float* __restrict__ pred, const int* __restrict__ lines,
        const float* __restrict__ mx, float* __restrict__ partials) {
    __shared__ float wsum[WAVES_PER_BLOCK];
    int lane = threadIdx.x & 63;
    int w = threadIdx.x >> 6;
    // XCD-aware swizzle: blocks round-robin XCDs by hardware dispatch; remap so
    // each XCD gets a contiguous chunk (4 batches -> 6.8 MB working set per L2).
    int bid = blockIdx.x;
    int swz = (bid & 7) * (NBLOCKS / 8) + (bid >> 3);
    int g = swz * WAVES_PER_BLOCK + w;   // global line id
    int b = g >> 9;                      // / LL

    int4 ln = ((const int4*)lines)[g];
    int x0 = min(max(ln.x, 0), WW - 1);
    int y0 = min(max(ln.y, 0), HH - 1);
    int x1 = min(max(ln.z, 0), WW - 1);
    int y1 = min(max(ln.w, 0), HH - 1);

    int dx = abs(x1 - x0), dy = abs(y1 - y0);
    bool xm = dx > dy;
    int dmaj = xm ? dx : dy;
    int dmin = xm ? dy : dx;
    int sx = (x1 > x0) - (x1 < x0);
    int sy = (y1 > y0) - (y1 < y0);
    int smaj = xm ? sx : sy;
    int smin = xm ? sy : sx;
    int maj0 = xm ? x0 : y0;
    int min0 = xm ? y0 : x0;

    const float* __restrict__ p = pred + (size_t)b * (HH * WW);

    float s = 0.0f;
    if (dmaj > 0) {
        int den = 2 * dmaj;
        int tdm = 2 * dmin;
        int c = (dmaj + 63) >> 6;        // path points (diffs) per lane
        int s0 = lane * c;               // this lane's first point index
        // Exact q,e at i=s0 (one divide per lane, preamble only):
        int num = tdm * s0 + dmaj;
        int q = (int)((unsigned)num / (unsigned)den);
        int e = num - q * den;           // e in [0, den)
        int mj = maj0 + smaj * s0;
        int mn = min0 + smin * q;
        int off = xm ? (mn * WW + mj) : (mj * WW + mn);
        int incA = xm ? smaj : smaj * WW;      // per-step major increment (elems)
        int incQ = xm ? smin * WW : smin;      // per-minor-step increment
        int inc0 = incA, inc1 = incA + incQ;
        float vp = (s0 <= dmaj) ? p[off] : 0.0f;
        for (int j = 0; j < c; ++j) {
            // advance one path step: e += 2*dmin; minor steps iff e >= 2*dmaj
            e += tdm;
            bool stepq = (e >= den);
            e -= stepq ? den : 0;
            off += stepq ? inc1 : inc0;
            int i = s0 + j + 1;
            if (i <= dmaj) {
                float v = p[off];
                s += fabsf(v - vp);
                vp = v;
            }
        }
    }
    // wave-level sum reduction (64 lanes)
    #pragma unroll
    for (int offr = 32; offr > 0; offr >>= 1) s += __shfl_down(s, offr);

    if (lane == 0) {
        // end_diff mask: vals[0] = pred[y0,x0], vals[-1] = pred[y1,x1]
        float vf = p[y0 * WW + x0];
        float vl = p[y1 * WW + x1];
        if (fabsf(vf - vl) < 0.5f) s = 0.0f;

        float deg = line_degree(x0, y0, x1, y1);
        float mxv = mx[b];
        float skewed = powf(deg, 1.5f) / powf(mxv + 1.0f, 0.5f);
        float t = fabsf(skewed - 45.0f);
        float h = 90.0f - powf(powf(t, 2.5f), 0.4f);
        float wgt = powf(h * (1.0f / 300.0f), 4.0f);
        wsum[w] = wgt * s;
    }
    __syncthreads();
    if (threadIdx.x == 0) {
        float acc = 0.0f;
        #pragma unroll
        for (int i = 0; i < WAVES_PER_BLOCK; ++i) acc += wsum[i];
        partials[blockIdx.x] = acc;
    }
}

__global__ void final_reduce_kernel(const float* __restrict__ partials,
                                    float* __restrict__ out) {
    __shared__ float red[256];
    int t = threadIdx.x;
    float s = 0.0f;
    for (int i = t; i < NBLOCKS; i += 256) s += partials[i];
    red[t] = s;
    __syncthreads();
    for (int k = 128; k > 0; k >>= 1) {
        if (t < k) red[t] += red[t + k];
        __syncthreads();
    }
    if (t == 0) out[0] = red[0];
}

extern "C" void kernel_launch(void* const* d_in, const int* in_sizes, int n_in,
                              void* d_out, int out_size, void* d_ws, size_t ws_size,
                              hipStream_t stream) {
    const float* pred = (const float*)d_in[0];
    const int* lines = (const int*)d_in[1];
    float* out = (float*)d_out;
    float* ws = (float*)d_ws;
    float* mx = ws;                 // 32 floats
    float* partials = ws + 32;      // 4096 floats

    deg_max_kernel<<<BB, LL, 0, stream>>>(lines, mx);
    line_walk_kernel<<<NBLOCKS, 256, 0, stream>>>(pred, lines, mx, partials);
    final_reduce_kernel<<<1, 256, 0, stream>>>(partials, out);
}

// Round 5
// 46.061 us; speedup vs baseline: 1.1735x; 1.1395x over previous
//
#include <hip/hip_runtime.h>
#include <math.h>

#define BB 32
#define LL 512
#define HH 352
#define WW 1216
#define NLINES (BB * LL)          // 16384
#define WAVES_PER_BLOCK 4
#define NBLOCKS (NLINES / WAVES_PER_BLOCK)  // 4096

__device__ __forceinline__ float line_degree(int x0, int y0, int x1, int y1) {
    // Replicates: slopes = |(y1f - y0f) / (x1f - x0f + 1e-6)|
    //             degrees = (arctan(slopes) * 180.0 / pi) % 90.0
    float slope = fabsf(((float)y1 - (float)y0) / ((float)x1 - (float)x0 + 1e-6f));
    float deg = (atanf(slope) * 180.0f) / 3.14159274101257324f;  // f32(pi)
    return fmodf(deg, 90.0f);
}

__global__ void deg_max_kernel(const int* __restrict__ lines, float* __restrict__ mx) {
    __shared__ float red[LL];
    int b = blockIdx.x;
    int t = threadIdx.x;
    int4 ln = ((const int4*)lines)[b * LL + t];
    int x0 = min(max(ln.x, 0), WW - 1);
    int y0 = min(max(ln.y, 0), HH - 1);
    int x1 = min(max(ln.z, 0), WW - 1);
    int y1 = min(max(ln.w, 0), HH - 1);
    red[t] = line_degree(x0, y0, x1, y1);
    __syncthreads();
    for (int s = LL / 2; s > 0; s >>= 1) {
        if (t < s) red[t] = fmaxf(red[t], red[t + s]);
        __syncthreads();
    }
    if (t == 0) mx[b] = red[0];
}

__global__ void __launch_bounds__(256) line_walk_kernel(
        const float* __restrict__ pred, const int* __restrict__ lines,
        const float* __restrict__ mx, float* __restrict__ partials) {
    __shared__ float wsum[WAVES_PER_BLOCK];
    int lane = threadIdx.x & 63;
    int w = threadIdx.x >> 6;
    // XCD-aware swizzle: each XCD gets a contiguous chunk of lines
    // (4 batches -> 6.8 MB working set per 4 MiB L2 + reuse).
    int bid = blockIdx.x;
    int swz = (bid & 7) * (NBLOCKS / 8) + (bid >> 3);
    int g = swz * WAVES_PER_BLOCK + w;   // global line id
    int b = g >> 9;                      // / LL

    int4 ln = ((const int4*)lines)[g];
    int x0 = min(max(ln.x, 0), WW - 1);
    int y0 = min(max(ln.y, 0), HH - 1);
    int x1 = min(max(ln.z, 0), WW - 1);
    int y1 = min(max(ln.w, 0), HH - 1);

    int dx = abs(x1 - x0), dy = abs(y1 - y0);
    bool xm = dx > dy;
    int dmaj = xm ? dx : dy;
    int dmin = xm ? dy : dx;
    int sx = (x1 > x0) - (x1 < x0);
    int sy = (y1 > y0) - (y1 < y0);
    int smaj = xm ? sx : sy;
    int smin = xm ? sy : sx;
    int maj0 = xm ? x0 : y0;
    int min0 = xm ? y0 : x0;

    const float* __restrict__ p = pred + (size_t)b * (HH * WW);

    float s = 0.0f;
    if (dmaj > 0) {
        int den = 2 * dmaj;
        int tdm = 2 * dmin;
        // Interleaved decomposition: at chunk j, lane i holds path point 64j+i.
        // Wave reads 64 consecutive path points -> coalesced (x-major: ~4
        // cache lines per load). One load per point; diffs via shuffles.
        int niter = (dmaj >> 6) + 1;     // chunks covering points 0..dmaj
        float prev_last = 0.0f;          // lane63's value from previous chunk
        for (int j = 0; j < niter; ++j) {
            int idx = (j << 6) + lane;
            int idc = min(idx, dmaj);    // clamp -> load always in-bounds
            int num = tdm * idc + dmaj;
            int q = (int)((unsigned)num / (unsigned)den);
            int mj = maj0 + smaj * idc;
            int mn = min0 + smin * q;
            int off = xm ? (mn * WW + mj) : (mj * WW + mn);
            float v = p[off];
            float vn = __shfl_down(v, 1);
            if (lane < 63 && idx + 1 <= dmaj) s += fabsf(vn - v);
            if (lane == 0 && j > 0) s += fabsf(v - prev_last);
            prev_last = __shfl(v, 63);
        }
    }
    // wave-level sum reduction (64 lanes)
    #pragma unroll
    for (int offr = 32; offr > 0; offr >>= 1) s += __shfl_down(s, offr);

    if (lane == 0) {
        // end_diff mask: vals[0] = pred[y0,x0], vals[-1] = pred[y1,x1]
        float vf = p[y0 * WW + x0];
        float vl = p[y1 * WW + x1];
        if (fabsf(vf - vl) < 0.5f) s = 0.0f;

        float deg = line_degree(x0, y0, x1, y1);
        float mxv = mx[b];
        float skewed = powf(deg, 1.5f) / powf(mxv + 1.0f, 0.5f);
        float t = fabsf(skewed - 45.0f);
        float h = 90.0f - powf(powf(t, 2.5f), 0.4f);
        float wgt = powf(h * (1.0f / 300.0f), 4.0f);
        wsum[w] = wgt * s;
    }
    __syncthreads();
    if (threadIdx.x == 0) {
        float acc = 0.0f;
        #pragma unroll
        for (int i = 0; i < WAVES_PER_BLOCK; ++i) acc += wsum[i];
        partials[blockIdx.x] = acc;
    }
}

__global__ void final_reduce_kernel(const float* __restrict__ partials,
                                    float* __restrict__ out) {
    __shared__ float red[256];
    int t = threadIdx.x;
    float s = 0.0f;
    for (int i = t; i < NBLOCKS; i += 256) s += partials[i];
    red[t] = s;
    __syncthreads();
    for (int k = 128; k > 0; k >>= 1) {
        if (t < k) red[t] += red[t + k];
        __syncthreads();
    }
    if (t == 0) out[0] = red[0];
}

extern "C" void kernel_launch(void* const* d_in, const int* in_sizes, int n_in,
                              void* d_out, int out_size, void* d_ws, size_t ws_size,
                              hipStream_t stream) {
    const float* pred = (const float*)d_in[0];
    const int* lines = (const int*)d_in[1];
    float* out = (float*)d_out;
    float* ws = (float*)d_ws;
    float* mx = ws;                 // 32 floats
    float* partials = ws + 32;      // 4096 floats

    deg_max_kernel<<<BB, LL, 0, stream>>>(lines, mx);
    line_walk_kernel<<<NBLOCKS, 256, 0, stream>>>(pred, lines, mx, partials);
    final_reduce_kernel<<<1, 256, 0, stream>>>(partials, out);
}